// Round 10
// baseline (565.849 us; speedup 1.0000x reference)
//
#include <hip/hip_runtime.h>
#include <math.h>

#define NROWS 8192
#define KDIM  768            // elements per row; for i8 buffers this is also BYTES
#define BM 128
#define BN 128
#define BKB 128              // K-tile bytes per row (128 i8 = 2 MFMA k-steps of 64)
#define KTILES (KDIM / BKB)  // 6
#define NBC 4                // bc tiles swept per block
#define NBCG (NROWS / BN / NBC)  // 16
#define NBLK ((NROWS / BM) * NBCG)  // 1024 blocks = 4/CU, fully co-resident

typedef int i32x4 __attribute__((ext_vector_type(4)));  // i8 MFMA A/B frag (16 B) and C/D

// monotonic float<->uint encoding so atomicMax(uint) == float max
static __device__ __forceinline__ unsigned enc_f(float f) {
    unsigned x = __float_as_uint(f);
    return (x & 0x80000000u) ? ~x : (x | 0x80000000u);
}
static __device__ __forceinline__ float dec_f(unsigned u) {
    unsigned x = (u & 0x80000000u) ? (u ^ 0x80000000u) : ~u;
    return __uint_as_float(x);
}

// Hand-rolled grid barrier (graph-capturable, unlike hipLaunchCooperativeKernel
// which the harness's graph capture silently drops — R9 lesson: out stayed
// memset-0, absmax == max|ref|). Legality: 32 KB LDS caps 5 blocks/CU;
// __launch_bounds__(256,4) guarantees >=4; grid 1024 = 256 CU x 4 <= capacity,
// so all blocks are resident before any spin. Visibility: agent-scope atomics
// bypass per-XCD L2 (coherent); __threadfence() emits gfx950 agent
// release/acquire (L2 writeback + inv) around the rendezvous.
static __device__ __forceinline__ void grid_barrier(unsigned* cnt, unsigned* gen) {
    __syncthreads();
    if (threadIdx.x == 0) {
        __threadfence();   // release: flush this block's prior writes
        const unsigned g = __hip_atomic_load(gen, __ATOMIC_ACQUIRE,
                                             __HIP_MEMORY_SCOPE_AGENT);
        const unsigned a = __hip_atomic_fetch_add(cnt, 1u, __ATOMIC_ACQ_REL,
                                                  __HIP_MEMORY_SCOPE_AGENT);
        if (a == NBLK - 1) {           // last to arrive: reset + release all
            __hip_atomic_store(cnt, 0u, __ATOMIC_RELAXED, __HIP_MEMORY_SCOPE_AGENT);
            __hip_atomic_fetch_add(gen, 1u, __ATOMIC_RELEASE, __HIP_MEMORY_SCOPE_AGENT);
        } else {
            while (__hip_atomic_load(gen, __ATOMIC_ACQUIRE,
                                     __HIP_MEMORY_SCOPE_AGENT) == g)
                __builtin_amdgcn_s_sleep(2);
        }
        __threadfence();   // acquire: invalidate stale lines before phase B reads
    }
    __syncthreads();
}

// ONE plain-launch kernel, three phases over hand-rolled grid barriers:
//  A) normalize+quant (fp32 exact norm, symmetric int8 amax/127/row);
//     blocks 0..31 also init the out buffer. 16 rows/block (4/wave).
//  B) R4-proven gemm (128^2 tile, 4 waves, chunk-XOR swizzle 0-conflict,
//     2-sync loop, 2D XCD decode -> 18.6 MB FETCH) + R8-verified hoisted
//     epilogue (running reg max; single shfl-tree+atomic pass).
//  C) in-place decode of the monotone-encoded out buffer.
// Rationale: bench_total - gemm_dur was a stable ~75-80 us across R1-R8 while
// normalize+decode first-principles cost is ~15 us -> bulk is kernel-boundary
// overhead; fusing removes 2 boundaries and 2 dispatches.
__global__ __launch_bounds__(256, 4) void fused_cosine_k(
        const float* __restrict__ ex, const float* __restrict__ ey,
        signed char* __restrict__ q, float* __restrict__ scales,
        unsigned* __restrict__ out, unsigned* bar) {
    __shared__ signed char As[BM * BKB];   // 16 KB
    __shared__ signed char Bs[BN * BKB];   // 16 KB

    const int tid  = threadIdx.x;
    const int wave = tid >> 6, lane = tid & 63;

    // ---------------- phase A: out-init + normalize/quant ----------------
    if (blockIdx.x < NROWS / 256)
        out[blockIdx.x * 256 + tid] = enc_f(-INFINITY);
    #pragma unroll 1
    for (int g = 0; g < 4; ++g) {
        const int grow = g * 4096 + blockIdx.x * 4 + wave;   // 0..16383
        const float* src = (grow < NROWS) ? ex : ey;
        const int row = grow & (NROWS - 1);
        const float4* xr = (const float4*)(src + (size_t)row * KDIM);  // 192 float4
        float4 v[3];
        #pragma unroll
        for (int c = 0; c < 3; ++c) v[c] = xr[lane + c * 64];
        float ss = 0.f, am = 0.f;
        #pragma unroll
        for (int c = 0; c < 3; ++c) {
            ss += v[c].x * v[c].x + v[c].y * v[c].y + v[c].z * v[c].z + v[c].w * v[c].w;
            am = fmaxf(am, fmaxf(fmaxf(fabsf(v[c].x), fabsf(v[c].y)),
                                 fmaxf(fabsf(v[c].z), fabsf(v[c].w))));
        }
        #pragma unroll
        for (int off = 32; off > 0; off >>= 1) {
            ss += __shfl_xor(ss, off);
            am = fmaxf(am, __shfl_xor(am, off));
        }
        const float scale = 1.0f / fmaxf(sqrtf(ss), 1e-8f);
        am = fmaxf(am * scale, 1e-12f);        // amax of the NORMALIZED row
        if (lane == 0) scales[grow] = am * (1.0f / 127.0f);
        const float si = scale * (127.0f / am);            // raw -> int8 code
        int* dr = (int*)(q + (size_t)grow * KDIM);         // 192 packed ints / row
        #pragma unroll
        for (int c = 0; c < 3; ++c) {
            int qx = min(127, max(-127, __float2int_rn(v[c].x * si)));
            int qy = min(127, max(-127, __float2int_rn(v[c].y * si)));
            int qz = min(127, max(-127, __float2int_rn(v[c].z * si)));
            int qw = min(127, max(-127, __float2int_rn(v[c].w * si)));
            dr[lane + c * 64] = (qx & 0xff) | ((qy & 0xff) << 8) |
                                ((qz & 0xff) << 16) | ((qw & 0xff) << 24);
        }
    }

    grid_barrier(bar, bar + 1);   // q + scales + out-init visible device-wide

    // ---------------- phase B: gemm + row-max (R4-proven) ----------------
    const signed char* A = q;
    const signed char* B = q + (size_t)NROWS * KDIM;
    const float* sa = scales;
    const float* sb = scales + NROWS;

    // 2D XCD-aware decode (R4-proven: 16br x 8bcg rectangle per XCD, 4.7 MB
    // working set ~= L2, all 128 blocks/XCD co-resident). Bijective.
    const int xcd = blockIdx.x & 7;        // dispatch round-robins XCDs
    const int idx = blockIdx.x >> 3;       // 0..127 within XCD
    const int br  = (xcd >> 1) * 16 + (idx & 15);   // 0..63
    const int bcg = (xcd & 1) * 8 + (idx >> 4);     // 0..15

    // staging: wave issue = 8 rows x 128 B; slot s of row r holds chunk s^(r&7)
    const int srow   = lane >> 3;
    const int gchunk = (lane & 7) ^ srow;
    const int scol   = gchunk * 16;        // bytes
    const signed char* aStage = A + (size_t)(br * BM + wave * 8 + srow) * KDIM + scol;
    signed char* lA = As + wave * 1024;    // + i*4096
    signed char* lB = Bs + wave * 1024;

    // compute geometry: wave 64x64, 4x4 tiles of 16x16x64
    const int wm = (wave >> 1) * 64, wn = (wave & 1) * 64;
    const int quad = lane >> 4, mrow = lane & 15;
    const int c0 = quad ^ (mrow & 7);      // swizzled chunk slot; ks=1: ^4
    const signed char* aBase = As + (wm + mrow) * BKB;
    const signed char* bBase = Bs + (wn + mrow) * BKB;
    const int row0 = br * BM + wm + quad * 4;

    // running row-max across the whole bc sweep (hoisted epilogue, R8-verified)
    float rm[4][4];
    #pragma unroll
    for (int mi = 0; mi < 4; ++mi)
        #pragma unroll
        for (int r = 0; r < 4; ++r) rm[mi][r] = -INFINITY;

    #pragma unroll 1
    for (int bi = 0; bi < NBC; ++bi) {
        const int bc = bcg * NBC + bi;
        const signed char* bStage =
            B + (size_t)(bc * BN + wave * 8 + srow) * KDIM + scol;

        i32x4 acc[4][4] = {};

        #pragma unroll 1
        for (int kt = 0; kt < KTILES; ++kt) {
            __syncthreads();   // previous tile's LDS reads done
            #pragma unroll
            for (int i = 0; i < 4; ++i) {
                __builtin_amdgcn_global_load_lds(
                    (const __attribute__((address_space(1))) void*)(aStage + kt * BKB + i * 24576),
                    (__attribute__((address_space(3))) void*)(lA + i * 4096), 16, 0, 0);
                __builtin_amdgcn_global_load_lds(
                    (const __attribute__((address_space(1))) void*)(bStage + kt * BKB + i * 24576),
                    (__attribute__((address_space(3))) void*)(lB + i * 4096), 16, 0, 0);
            }
            __syncthreads();   // staging complete

            #pragma unroll 1
            for (int ks = 0; ks < 2; ++ks) {
                const int ck = c0 ^ (ks << 2);
                i32x4 af[4], bfr[4];
                #pragma unroll
                for (int mi = 0; mi < 4; ++mi)
                    af[mi] = *(const i32x4*)(aBase + mi * 16 * BKB + ck * 16);
                #pragma unroll
                for (int ni = 0; ni < 4; ++ni)
                    bfr[ni] = *(const i32x4*)(bBase + ni * 16 * BKB + ck * 16);
                #pragma unroll
                for (int mi = 0; mi < 4; ++mi)
                    #pragma unroll
                    for (int ni = 0; ni < 4; ++ni)
                        acc[mi][ni] = __builtin_amdgcn_mfma_i32_16x16x64_i8(
                            af[mi], bfr[ni], acc[mi][ni], 0, 0, 0);
            }
        }

        // fold sb[col] per ni and keep running in-register max
        float sbv[4];
        #pragma unroll
        for (int ni = 0; ni < 4; ++ni)
            sbv[ni] = sb[bc * BN + wn + ni * 16 + mrow];
        #pragma unroll
        for (int mi = 0; mi < 4; ++mi) {
            #pragma unroll
            for (int r = 0; r < 4; ++r) {
                float v = fmaxf(fmaxf((float)acc[mi][0][r] * sbv[0],
                                      (float)acc[mi][1][r] * sbv[1]),
                                fmaxf((float)acc[mi][2][r] * sbv[2],
                                      (float)acc[mi][3][r] * sbv[3]));
                rm[mi][r] = fmaxf(rm[mi][r], v);
            }
        }
    }

    // deferred epilogue: shfl-max over 16 cols, *sa[row] (sa>0 commutes),
    // one atomic per (mi,r,quad). C/D layout: col = lane&15, row = quad*4+reg.
    #pragma unroll
    for (int mi = 0; mi < 4; ++mi) {
        #pragma unroll
        for (int r = 0; r < 4; ++r) {
            float v = rm[mi][r];
            v = fmaxf(v, __shfl_xor(v, 1));
            v = fmaxf(v, __shfl_xor(v, 2));
            v = fmaxf(v, __shfl_xor(v, 4));
            v = fmaxf(v, __shfl_xor(v, 8));
            if (mrow == 0) {
                const int row = row0 + mi * 16 + r;
                atomicMax(&out[row], enc_f(v * sa[row]));
            }
        }
    }

    grid_barrier(bar, bar + 1);   // all atomics visible device-wide

    // ---------------- phase C: decode out in place ----------------
    if (blockIdx.x < NROWS / 256) {
        const int i = blockIdx.x * 256 + tid;
        const unsigned u = out[i];
        ((float*)out)[i] = dec_f(u);
    }
}

extern "C" void kernel_launch(void* const* d_in, const int* in_sizes, int n_in,
                              void* d_out, int out_size, void* d_ws, size_t ws_size,
                              hipStream_t stream) {
    (void)in_sizes; (void)n_in; (void)out_size; (void)ws_size;
    const float* ex = (const float*)d_in[0];
    const float* ey = (const float*)d_in[1];
    // ws layout: qx[8192*768 B] ++ qy[8192*768 B] ++ scales[16384 f32]
    //            ++ barrier{cnt,gen}[2 u32]   (~12.65 MB)
    signed char* q = (signed char*)d_ws;
    float* scales  = (float*)(q + 2 * (size_t)NROWS * KDIM);
    unsigned* bar  = (unsigned*)(scales + 2 * NROWS);
    unsigned* outu = (unsigned*)d_out;

    hipMemsetAsync(bar, 0, 2 * sizeof(unsigned), stream);
    fused_cosine_k<<<NBLK, 256, 0, stream>>>(ex, ey, q, scales, outu, bar);
}

// Round 11
// 341.379 us; speedup vs baseline: 1.6575x; 1.6575x over previous
//
#include <hip/hip_runtime.h>
#include <math.h>

#define NROWS 8192
#define KDIM  768            // elements per row; for i8 buffers this is also BYTES
#define BM 128
#define BN 128
#define KT12 (KDIM / 64)     // 12 k-steps of 64 (one 16x16x64 MFMA each)
#define NBC 4                // bc tiles swept per block
#define NBCG (NROWS / BN / NBC)  // 16
#define NBLK ((NROWS / BM) * NBCG)  // 1024 blocks = 4/CU

typedef int i32x4 __attribute__((ext_vector_type(4)));  // i8 MFMA A/B frag (16 B) and C/D

// monotonic float<->uint encoding so atomicMax(uint) == float max
static __device__ __forceinline__ unsigned enc_f(float f) {
    unsigned x = __float_as_uint(f);
    return (x & 0x80000000u) ? ~x : (x | 0x80000000u);
}
static __device__ __forceinline__ float dec_f(unsigned u) {
    unsigned x = (u & 0x80000000u) ? (u ^ 0x80000000u) : ~u;
    return __uint_as_float(x);
}

// one wave per row: fp32 normalize (exact), then symmetric int8 quantization
// with per-row scale amax/127. blocks 0..31 also init the out buffer.
__global__ __launch_bounds__(256) void normalize_quant_k(
        const float* __restrict__ ex, const float* __restrict__ ey,
        signed char* __restrict__ q, float* __restrict__ scales,
        unsigned* __restrict__ out) {
    if (blockIdx.x < NROWS / 256)
        out[blockIdx.x * 256 + threadIdx.x] = enc_f(-INFINITY);
    const int wave = threadIdx.x >> 6, lane = threadIdx.x & 63;
    const int grow = blockIdx.x * 4 + wave;          // 0..16383
    const float* src = (grow < NROWS) ? ex : ey;
    const int row = grow & (NROWS - 1);
    const float4* xr = (const float4*)(src + (size_t)row * KDIM);  // 192 float4
    float4 v[3];
    #pragma unroll
    for (int g = 0; g < 3; ++g) v[g] = xr[lane + g * 64];
    float ss = 0.f, am = 0.f;
    #pragma unroll
    for (int g = 0; g < 3; ++g) {
        ss += v[g].x * v[g].x + v[g].y * v[g].y + v[g].z * v[g].z + v[g].w * v[g].w;
        am = fmaxf(am, fmaxf(fmaxf(fabsf(v[g].x), fabsf(v[g].y)),
                             fmaxf(fabsf(v[g].z), fabsf(v[g].w))));
    }
    #pragma unroll
    for (int off = 32; off > 0; off >>= 1) {
        ss += __shfl_xor(ss, off);
        am = fmaxf(am, __shfl_xor(am, off));
    }
    const float scale = 1.0f / fmaxf(sqrtf(ss), 1e-8f);
    am = fmaxf(am * scale, 1e-12f);        // amax of the NORMALIZED row
    if (lane == 0) scales[grow] = am * (1.0f / 127.0f);
    const float si = scale * (127.0f / am);            // raw -> int8 code
    int* dr = (int*)(q + (size_t)grow * KDIM);         // 192 packed ints / row
    #pragma unroll
    for (int g = 0; g < 3; ++g) {
        int qx = min(127, max(-127, __float2int_rn(v[g].x * si)));
        int qy = min(127, max(-127, __float2int_rn(v[g].y * si)));
        int qz = min(127, max(-127, __float2int_rn(v[g].z * si)));
        int qw = min(127, max(-127, __float2int_rn(v[g].w * si)));
        dr[lane + g * 64] = (qx & 0xff) | ((qy & 0xff) << 8) |
                            ((qz & 0xff) << 16) | ((qw & 0xff) << 24);
    }
}

// NO-LDS gemm: A/B fragments loaded straight from global (L2-resident via the
// R4-proven XCD rectangle) into registers. The MFMA operand layout
// (frag[lane] = M[rowbase + (lane&15)][kt*64 + (lane>>4)*16 .. +16], verified
// by every passing round) is directly loadable: one global dwordx4 per frag =
// 16 rows x 64 contiguous bytes. NO __syncthreads anywhere -> the barrier-drain
// that pinned R4-R8 at 26% MfmaUtil is gone; 16 waves/CU of free-running TLP
// + compiler scheduling in the barrier-free unrolled body hide VMEM latency.
// Cost accepted: 2x intra-block redundancy (waves 0,1 / 2,3 share A rows;
// 0,2 / 1,3 share B cols) -> 1.6 GB from L2 ~= 47 B/cy/CU over ~55 us, within
// the ~56 B/cy/CU per-CU L2 share.
// Epilogue: R8-verified hoisted running max + one atomic pass; then last-block
// ticket (threadfence + agent-scope RMW, m20) decodes out in place — kills the
// 3rd kernel launch.
__global__ __launch_bounds__(256, 4) void gemm_rowmax_i8_k(
        const signed char* __restrict__ A, const signed char* __restrict__ B,
        const float* __restrict__ sa, const float* __restrict__ sb,
        unsigned* __restrict__ out, unsigned* __restrict__ ticket) {
    const int tid  = threadIdx.x;
    const int wave = tid >> 6, lane = tid & 63;
    // 2D XCD-aware decode (R4-proven: 16br x 8bcg rectangle per XCD, 4.7 MB
    // working set ~= L2, all 128 blocks/XCD co-resident). Bijective.
    const int xcd = blockIdx.x & 7;        // dispatch round-robins XCDs
    const int idx = blockIdx.x >> 3;       // 0..127 within XCD
    const int br  = (xcd >> 1) * 16 + (idx & 15);   // 0..63
    const int bcg = (xcd & 1) * 8 + (idx >> 4);     // 0..15

    // compute geometry: wave 64x64, 4x4 tiles of 16x16x64
    const int wm = (wave >> 1) * 64, wn = (wave & 1) * 64;
    const int quad = lane >> 4, mrow = lane & 15;
    const int row0 = br * BM + wm + quad * 4;

    // per-lane fragment base pointers (A operand: row = mrow + mi*16,
    // k-chunk = quad*16 within each kt*64 slice; B operand identical on cols)
    const signed char* aP =
        A + (size_t)(br * BM + wm + mrow) * KDIM + quad * 16;

    // running row-max across the whole bc sweep (hoisted epilogue, R8-verified)
    float rm[4][4];
    #pragma unroll
    for (int mi = 0; mi < 4; ++mi)
        #pragma unroll
        for (int r = 0; r < 4; ++r) rm[mi][r] = -INFINITY;

    #pragma unroll 1
    for (int bi = 0; bi < NBC; ++bi) {
        const int bc = bcg * NBC + bi;
        const signed char* bP =
            B + (size_t)(bc * BN + wn + mrow) * KDIM + quad * 16;

        i32x4 acc[4][4] = {};

        #pragma unroll 2
        for (int kt = 0; kt < KT12; ++kt) {
            i32x4 af[4], bfr[4];
            #pragma unroll
            for (int mi = 0; mi < 4; ++mi)
                af[mi] = *(const i32x4*)(aP + (size_t)mi * 16 * KDIM + kt * 64);
            #pragma unroll
            for (int ni = 0; ni < 4; ++ni)
                bfr[ni] = *(const i32x4*)(bP + (size_t)ni * 16 * KDIM + kt * 64);
            #pragma unroll
            for (int mi = 0; mi < 4; ++mi)
                #pragma unroll
                for (int ni = 0; ni < 4; ++ni)
                    acc[mi][ni] = __builtin_amdgcn_mfma_i32_16x16x64_i8(
                        af[mi], bfr[ni], acc[mi][ni], 0, 0, 0);
        }

        // fold sb[col] per ni and keep running in-register max
        float sbv[4];
        #pragma unroll
        for (int ni = 0; ni < 4; ++ni)
            sbv[ni] = sb[bc * BN + wn + ni * 16 + mrow];
        #pragma unroll
        for (int mi = 0; mi < 4; ++mi) {
            #pragma unroll
            for (int r = 0; r < 4; ++r) {
                float v = fmaxf(fmaxf((float)acc[mi][0][r] * sbv[0],
                                      (float)acc[mi][1][r] * sbv[1]),
                                fmaxf((float)acc[mi][2][r] * sbv[2],
                                      (float)acc[mi][3][r] * sbv[3]));
                rm[mi][r] = fmaxf(rm[mi][r], v);
            }
        }
    }

    // deferred epilogue: shfl-max over 16 cols, *sa[row] (sa>0 commutes),
    // one atomic per (mi,r,quad). C/D layout: col = lane&15, row = quad*4+reg.
    #pragma unroll
    for (int mi = 0; mi < 4; ++mi) {
        #pragma unroll
        for (int r = 0; r < 4; ++r) {
            float v = rm[mi][r];
            v = fmaxf(v, __shfl_xor(v, 1));
            v = fmaxf(v, __shfl_xor(v, 2));
            v = fmaxf(v, __shfl_xor(v, 4));
            v = fmaxf(v, __shfl_xor(v, 8));
            if (mrow == 0) {
                const int row = row0 + mi * 16 + r;
                atomicMax(&out[row], enc_f(v * sa[row]));
            }
        }
    }

    // ---- last-block decode (kills the 3rd kernel launch) ----
    // Each block: release-fence its atomics, then take a ticket. The block
    // that sees NBLK-1 knows every other block's atomics are globally visible
    // (their fences precede their RMWs; agent-scope RMWs are coherent, m20).
    __shared__ unsigned lastFlag;
    __threadfence();                       // release: my atomics visible
    __syncthreads();                       // all waves' atomics issued+fenced
    if (tid == 0)
        lastFlag = (__hip_atomic_fetch_add(ticket, 1u, __ATOMIC_ACQ_REL,
                                           __HIP_MEMORY_SCOPE_AGENT)
                    == (unsigned)(NBLK - 1));
    __syncthreads();
    if (lastFlag) {
        __threadfence();                   // acquire: see everyone's atomics
        for (int i = tid; i < NROWS; i += 256) {
            const unsigned u = __hip_atomic_load(&out[i], __ATOMIC_RELAXED,
                                                 __HIP_MEMORY_SCOPE_AGENT);
            ((float*)out)[i] = dec_f(u);
        }
    }
}

extern "C" void kernel_launch(void* const* d_in, const int* in_sizes, int n_in,
                              void* d_out, int out_size, void* d_ws, size_t ws_size,
                              hipStream_t stream) {
    (void)in_sizes; (void)n_in; (void)out_size; (void)ws_size;
    const float* ex = (const float*)d_in[0];
    const float* ey = (const float*)d_in[1];
    // ws layout: qx[8192*768 B] ++ qy[8192*768 B] ++ scales[16384 f32]
    //            ++ ticket[1 u32]   (~12.65 MB)
    signed char* q = (signed char*)d_ws;
    float* scales  = (float*)(q + 2 * (size_t)NROWS * KDIM);
    unsigned* ticket = (unsigned*)(scales + 2 * NROWS);
    unsigned* outu = (unsigned*)d_out;

    hipMemsetAsync(ticket, 0, sizeof(unsigned), stream);
    normalize_quant_k<<<(2 * NROWS) / 4, 256, 0, stream>>>(ex, ey, q, scales, outu);
    gemm_rowmax_i8_k<<<NBLK, 256, 0, stream>>>(
        q, q + (size_t)NROWS * KDIM, scales, scales + NROWS, outu, ticket);
}

// Round 13
// 223.965 us; speedup vs baseline: 2.5265x; 1.5242x over previous
//
#include <hip/hip_runtime.h>
#include <math.h>

#define NROWS 8192
#define KDIM  768            // elements per row; for i8 buffers this is also BYTES
#define BM 128
#define BN 128
#define BKB 128              // K-tile bytes per row (128 i8 = 2 MFMA k-steps of 64)
#define KTILES (KDIM / BKB)  // 6
#define NBC 4                // bc tiles swept per block
#define NBCG (NROWS / BN / NBC)  // 16
#define NBLK ((NROWS / BM) * NBCG)  // 1024 blocks = 4/CU

typedef int i32x4 __attribute__((ext_vector_type(4)));  // i8 MFMA A/B frag (16 B) and C/D

// monotonic float<->uint encoding so atomicMax(uint) == float max
static __device__ __forceinline__ unsigned enc_f(float f) {
    unsigned x = __float_as_uint(f);
    return (x & 0x80000000u) ? ~x : (x | 0x80000000u);
}
static __device__ __forceinline__ float dec_f(unsigned u) {
    unsigned x = (u & 0x80000000u) ? (u ^ 0x80000000u) : ~u;
    return __uint_as_float(x);
}

// one wave per row: fp32 normalize (exact), then symmetric int8 quantization
// with per-row scale amax/127. blocks 0..31 also init the out buffer.
__global__ __launch_bounds__(256) void normalize_quant_k(
        const float* __restrict__ ex, const float* __restrict__ ey,
        signed char* __restrict__ q, float* __restrict__ scales,
        unsigned* __restrict__ out) {
    if (blockIdx.x < NROWS / 256)
        out[blockIdx.x * 256 + threadIdx.x] = enc_f(-INFINITY);
    const int wave = threadIdx.x >> 6, lane = threadIdx.x & 63;
    const int grow = blockIdx.x * 4 + wave;          // 0..16383
    const float* src = (grow < NROWS) ? ex : ey;
    const int row = grow & (NROWS - 1);
    const float4* xr = (const float4*)(src + (size_t)row * KDIM);  // 192 float4
    float4 v[3];
    #pragma unroll
    for (int g = 0; g < 3; ++g) v[g] = xr[lane + g * 64];
    float ss = 0.f, am = 0.f;
    #pragma unroll
    for (int g = 0; g < 3; ++g) {
        ss += v[g].x * v[g].x + v[g].y * v[g].y + v[g].z * v[g].z + v[g].w * v[g].w;
        am = fmaxf(am, fmaxf(fmaxf(fabsf(v[g].x), fabsf(v[g].y)),
                             fmaxf(fabsf(v[g].z), fabsf(v[g].w))));
    }
    #pragma unroll
    for (int off = 32; off > 0; off >>= 1) {
        ss += __shfl_xor(ss, off);
        am = fmaxf(am, __shfl_xor(am, off));
    }
    const float scale = 1.0f / fmaxf(sqrtf(ss), 1e-8f);
    am = fmaxf(am * scale, 1e-12f);        // amax of the NORMALIZED row
    if (lane == 0) scales[grow] = am * (1.0f / 127.0f);
    const float si = scale * (127.0f / am);            // raw -> int8 code
    int* dr = (int*)(q + (size_t)grow * KDIM);         // 192 packed ints / row
    #pragma unroll
    for (int g = 0; g < 3; ++g) {
        int qx = min(127, max(-127, __float2int_rn(v[g].x * si)));
        int qy = min(127, max(-127, __float2int_rn(v[g].y * si)));
        int qz = min(127, max(-127, __float2int_rn(v[g].z * si)));
        int qw = min(127, max(-127, __float2int_rn(v[g].w * si)));
        dr[lane + g * 64] = (qx & 0xff) | ((qy & 0xff) << 8) |
                            ((qz & 0xff) << 16) | ((qw & 0xff) << 24);
    }
}

// Consolidation of harness-proven pieces only:
//  - R4 gemm verbatim: 128^2 tile, 4 waves, chunk-XOR swizzle (0 conflicts),
//    2-sync loop, 2D XCD decode (FETCH 102->18.6 MB), 4 blocks/CU. The 2-sync
//    loop dedicates ALL LDS to in-flight staging (4x32 KB/CU) — every
//    pipelined variant (R3/R5/R6) halved that window and lost.
//  - R8-verified hoisted epilogue: running reg max, ONE shfl/atomic pass
//    (R8's regression was its 2048-block grid thrashing L2, not the hoist;
//    grid here stays 1024 fully-resident).
//  - R11-verified last-block ticket decode: deletes the 3rd dispatch.
__global__ __launch_bounds__(256, 4) void gemm_rowmax_i8_k(
        const signed char* __restrict__ A, const signed char* __restrict__ B,
        const float* __restrict__ sa, const float* __restrict__ sb,
        unsigned* __restrict__ out, unsigned* __restrict__ ticket) {
    __shared__ signed char As[BM * BKB];   // 16 KB
    __shared__ signed char Bs[BN * BKB];   // 16 KB

    const int tid  = threadIdx.x;
    const int wave = tid >> 6, lane = tid & 63;
    // 2D XCD-aware decode (R4-proven: 16br x 8bcg rectangle per XCD, 4.7 MB
    // working set ~= L2, all 128 blocks/XCD co-resident). Bijective.
    const int xcd = blockIdx.x & 7;        // dispatch round-robins XCDs
    const int idx = blockIdx.x >> 3;       // 0..127 within XCD
    const int br  = (xcd >> 1) * 16 + (idx & 15);   // 0..63
    const int bcg = (xcd & 1) * 8 + (idx >> 4);     // 0..15

    // staging: wave issue = 8 rows x 128 B; slot s of row r holds chunk s^(r&7)
    const int srow   = lane >> 3;
    const int gchunk = (lane & 7) ^ srow;
    const int scol   = gchunk * 16;        // bytes
    const signed char* aStage = A + (size_t)(br * BM + wave * 8 + srow) * KDIM + scol;
    signed char* lA = As + wave * 1024;    // + i*4096
    signed char* lB = Bs + wave * 1024;

    // compute geometry: wave 64x64, 4x4 tiles of 16x16x64
    const int wm = (wave >> 1) * 64, wn = (wave & 1) * 64;
    const int quad = lane >> 4, mrow = lane & 15;
    const int c0 = quad ^ (mrow & 7);      // swizzled chunk slot; ks=1: ^4
    const signed char* aBase = As + (wm + mrow) * BKB;
    const signed char* bBase = Bs + (wn + mrow) * BKB;
    const int row0 = br * BM + wm + quad * 4;

    // running row-max across the whole bc sweep (hoisted epilogue, R8-verified)
    float rm[4][4];
    #pragma unroll
    for (int mi = 0; mi < 4; ++mi)
        #pragma unroll
        for (int r = 0; r < 4; ++r) rm[mi][r] = -INFINITY;

    #pragma unroll 1
    for (int bi = 0; bi < NBC; ++bi) {
        const int bc = bcg * NBC + bi;
        const signed char* bStage =
            B + (size_t)(bc * BN + wave * 8 + srow) * KDIM + scol;

        i32x4 acc[4][4] = {};

        #pragma unroll 1
        for (int kt = 0; kt < KTILES; ++kt) {
            __syncthreads();   // previous tile's LDS reads done
            #pragma unroll
            for (int i = 0; i < 4; ++i) {
                __builtin_amdgcn_global_load_lds(
                    (const __attribute__((address_space(1))) void*)(aStage + kt * BKB + i * 24576),
                    (__attribute__((address_space(3))) void*)(lA + i * 4096), 16, 0, 0);
                __builtin_amdgcn_global_load_lds(
                    (const __attribute__((address_space(1))) void*)(bStage + kt * BKB + i * 24576),
                    (__attribute__((address_space(3))) void*)(lB + i * 4096), 16, 0, 0);
            }
            __syncthreads();   // staging complete

            #pragma unroll 1
            for (int ks = 0; ks < 2; ++ks) {
                const int ck = c0 ^ (ks << 2);
                i32x4 af[4], bfr[4];
                #pragma unroll
                for (int mi = 0; mi < 4; ++mi)
                    af[mi] = *(const i32x4*)(aBase + mi * 16 * BKB + ck * 16);
                #pragma unroll
                for (int ni = 0; ni < 4; ++ni)
                    bfr[ni] = *(const i32x4*)(bBase + ni * 16 * BKB + ck * 16);
                #pragma unroll
                for (int mi = 0; mi < 4; ++mi)
                    #pragma unroll
                    for (int ni = 0; ni < 4; ++ni)
                        acc[mi][ni] = __builtin_amdgcn_mfma_i32_16x16x64_i8(
                            af[mi], bfr[ni], acc[mi][ni], 0, 0, 0);
            }
        }

        // fold sb[col] per ni and keep running in-register max
        float sbv[4];
        #pragma unroll
        for (int ni = 0; ni < 4; ++ni)
            sbv[ni] = sb[bc * BN + wn + ni * 16 + mrow];
        #pragma unroll
        for (int mi = 0; mi < 4; ++mi) {
            #pragma unroll
            for (int r = 0; r < 4; ++r) {
                float v = fmaxf(fmaxf((float)acc[mi][0][r] * sbv[0],
                                      (float)acc[mi][1][r] * sbv[1]),
                                fmaxf((float)acc[mi][2][r] * sbv[2],
                                      (float)acc[mi][3][r] * sbv[3]));
                rm[mi][r] = fmaxf(rm[mi][r], v);
            }
        }
    }

    // deferred epilogue: shfl-max over 16 cols, *sa[row] (sa>0 commutes),
    // one atomic per (mi,r,quad). C/D layout: col = lane&15, row = quad*4+reg.
    #pragma unroll
    for (int mi = 0; mi < 4; ++mi) {
        #pragma unroll
        for (int r = 0; r < 4; ++r) {
            float v = rm[mi][r];
            v = fmaxf(v, __shfl_xor(v, 1));
            v = fmaxf(v, __shfl_xor(v, 2));
            v = fmaxf(v, __shfl_xor(v, 4));
            v = fmaxf(v, __shfl_xor(v, 8));
            if (mrow == 0) {
                const int row = row0 + mi * 16 + r;
                atomicMax(&out[row], enc_f(v * sa[row]));
            }
        }
    }

    // ---- last-block decode (R11-verified; kills the 3rd kernel launch) ----
    __shared__ unsigned lastFlag;
    __threadfence();                       // release: my atomics visible
    __syncthreads();                       // all waves' atomics issued+fenced
    if (tid == 0)
        lastFlag = (__hip_atomic_fetch_add(ticket, 1u, __ATOMIC_ACQ_REL,
                                           __HIP_MEMORY_SCOPE_AGENT)
                    == (unsigned)(NBLK - 1));
    __syncthreads();
    if (lastFlag) {
        __threadfence();                   // acquire: see everyone's atomics
        for (int i = tid; i < NROWS; i += 256) {
            const unsigned u = __hip_atomic_load(&out[i], __ATOMIC_RELAXED,
                                                 __HIP_MEMORY_SCOPE_AGENT);
            ((float*)out)[i] = dec_f(u);
        }
    }
}

extern "C" void kernel_launch(void* const* d_in, const int* in_sizes, int n_in,
                              void* d_out, int out_size, void* d_ws, size_t ws_size,
                              hipStream_t stream) {
    (void)in_sizes; (void)n_in; (void)out_size; (void)ws_size;
    const float* ex = (const float*)d_in[0];
    const float* ey = (const float*)d_in[1];
    // ws layout: qx[8192*768 B] ++ qy[8192*768 B] ++ scales[16384 f32]
    //            ++ ticket[1 u32]   (~12.65 MB)
    signed char* q = (signed char*)d_ws;
    float* scales  = (float*)(q + 2 * (size_t)NROWS * KDIM);
    unsigned* ticket = (unsigned*)(scales + 2 * NROWS);
    unsigned* outu = (unsigned*)d_out;

    hipMemsetAsync(ticket, 0, sizeof(unsigned), stream);
    normalize_quant_k<<<(2 * NROWS) / 4, 256, 0, stream>>>(ex, ey, q, scales, outu);
    gemm_rowmax_i8_k<<<NBLK, 256, 0, stream>>>(
        q, q + (size_t)NROWS * KDIM, scales, scales + NROWS, outu, ticket);
}